// Round 1
// baseline (2008.805 us; speedup 1.0000x reference)
//
#include <hip/hip_runtime.h>
#include <hip/hip_bf16.h>
#include <cstdint>

#define HDIM 256
#define H2   128

// ---------------------------------------------------------------------------
// init: deg=1 (self loop), cursor=0, pooled=0, counts=0
__global__ void k_init(int* __restrict__ deg, int* __restrict__ cursor,
                       float* __restrict__ pooled, float* __restrict__ counts,
                       int n, int bh, int b) {
    int i = blockIdx.x * blockDim.x + threadIdx.x;
    if (i < n) { deg[i] = 1; cursor[i] = 0; }
    if (i < bh) pooled[i] = 0.f;
    if (i < b)  counts[i] = 0.f;
}

// in-degree via atomics over target column
__global__ void k_deg(const int* __restrict__ col, int* __restrict__ deg, int e) {
    int i = blockIdx.x * blockDim.x + threadIdx.x;
    if (i < e) atomicAdd(&deg[col[i]], 1);
}

// block-level exclusive scan of indeg (deg-1), pass 1: per-block scan + block sums
__global__ void k_scan1(const int* __restrict__ deg, int* __restrict__ ptr,
                        int* __restrict__ bsum, int n) {
    __shared__ int sd[256];
    int i = blockIdx.x * 256 + threadIdx.x;
    int v = (i < n) ? (deg[i] - 1) : 0;
    sd[threadIdx.x] = v;
    __syncthreads();
    for (int off = 1; off < 256; off <<= 1) {
        int t = (threadIdx.x >= off) ? sd[threadIdx.x - off] : 0;
        __syncthreads();
        sd[threadIdx.x] += t;
        __syncthreads();
    }
    if (i < n) ptr[i] = sd[threadIdx.x] - v;          // local exclusive
    if (threadIdx.x == 255) bsum[blockIdx.x] = sd[255];
}

// pass 2: single-block exclusive scan of block sums (nb <= 512)
__global__ void k_scan2(int* __restrict__ bsum, int nb) {
    __shared__ int sd[512];
    int t = threadIdx.x;
    int v = (t < nb) ? bsum[t] : 0;
    sd[t] = v;
    __syncthreads();
    for (int off = 1; off < 512; off <<= 1) {
        int x = (t >= off) ? sd[t - off] : 0;
        __syncthreads();
        sd[t] += x;
        __syncthreads();
    }
    if (t < nb) bsum[t] = sd[t] - v;                  // exclusive
}

// pass 3: add block offsets
__global__ void k_scan3(int* __restrict__ ptr, const int* __restrict__ bsum, int n) {
    int i = blockIdx.x * 256 + threadIdx.x;
    if (i < n) ptr[i] += bsum[blockIdx.x];
}

// fill CSR source lists (order within a destination irrelevant for a sum)
__global__ void k_fill(const int* __restrict__ row, const int* __restrict__ col,
                       const int* __restrict__ ptr, int* __restrict__ cursor,
                       int* __restrict__ csr_src, int e) {
    int i = blockIdx.x * blockDim.x + threadIdx.x;
    if (i < e) {
        int v = col[i];
        int s = atomicAdd(&cursor[v], 1);
        csr_src[ptr[v] + s] = row[i];
    }
}

// dis = deg^-0.5 ; per-graph node counts
__global__ void k_dis(const int* __restrict__ deg, float* __restrict__ dis,
                      const int* __restrict__ batch, float* __restrict__ counts, int n) {
    int i = blockIdx.x * blockDim.x + threadIdx.x;
    if (i < n) {
        dis[i] = rsqrtf((float)deg[i]);
        atomicAdd(&counts[batch[i]], 1.0f);
    }
}

// AtomEncoder: h[n, t] = sum_f emb[f, x[n,f], t]; block per node, t = column
__global__ __launch_bounds__(HDIM) void k_atom(const int* __restrict__ x,
                                               const float* __restrict__ emb,
                                               float* __restrict__ h,
                                               int n, int F, int V) {
    __shared__ int xs[16];
    int node = blockIdx.x, t = threadIdx.x;
    if (t < F) xs[t] = x[node * F + t];
    __syncthreads();
    float acc = 0.f;
    for (int f = 0; f < F; ++f)
        acc += emb[(f * V + xs[f]) * HDIM + t];
    h[node * HDIM + t] = acc;
}

// fp32 tiled GEMM: C[n, HDIM] = A[n, HDIM] @ W[HDIM, HDIM]
#define BM 64
#define BN 64
#define BK 16
__global__ __launch_bounds__(256) void k_gemm(const float* __restrict__ A,
                                              const float* __restrict__ W,
                                              float* __restrict__ C, int n) {
    __shared__ float As[BK][BM + 4];
    __shared__ float Bs[BK][BN + 4];
    int tid = threadIdx.x;
    int bm = blockIdx.x, bn = blockIdx.y;
    int tx = tid & 15, ty = tid >> 4;
    int row0 = bm * BM, col0 = bn * BN;
    float acc[4][4] = {};
    int a_k = tid & 15;      // k within tile
    int a_m = tid >> 4;      // row within tile (+16*l)
    int b_n = tid & 63;      // col within tile
    int b_k = tid >> 6;      // k within tile (+4*l)
    for (int kk = 0; kk < HDIM; kk += BK) {
#pragma unroll
        for (int l = 0; l < 4; ++l) {
            int m = a_m + l * 16;
            int gr = row0 + m;
            As[a_k][m] = (gr < n) ? A[(size_t)gr * HDIM + kk + a_k] : 0.f;
        }
#pragma unroll
        for (int l = 0; l < 4; ++l) {
            int k = b_k + l * 4;
            Bs[k][b_n] = W[(kk + k) * HDIM + col0 + b_n];
        }
        __syncthreads();
#pragma unroll
        for (int k = 0; k < BK; ++k) {
            float a[4], b[4];
#pragma unroll
            for (int i = 0; i < 4; ++i) a[i] = As[k][ty * 4 + i];
#pragma unroll
            for (int j = 0; j < 4; ++j) b[j] = Bs[k][tx * 4 + j];
#pragma unroll
            for (int i = 0; i < 4; ++i)
#pragma unroll
                for (int j = 0; j < 4; ++j) acc[i][j] += a[i] * b[j];
        }
        __syncthreads();
    }
#pragma unroll
    for (int i = 0; i < 4; ++i) {
        int gr = row0 + ty * 4 + i;
        if (gr < n) {
#pragma unroll
            for (int j = 0; j < 4; ++j)
                C[(size_t)gr * HDIM + col0 + tx * 4 + j] = acc[i][j];
        }
    }
}

// gather-aggregate + bias + relu + fused mean-pool accumulation
__global__ __launch_bounds__(HDIM) void k_agg(const float* __restrict__ m,
                                              const int* __restrict__ csr_src,
                                              const int* __restrict__ ptr,
                                              const int* __restrict__ deg,
                                              const float* __restrict__ dis,
                                              const float* __restrict__ bias,
                                              const int* __restrict__ batch,
                                              float* __restrict__ xout,
                                              float* __restrict__ pooled, int n) {
    int v = blockIdx.x, t = threadIdx.x;
    float dv = dis[v];
    float acc = bias[t] + dv * dv * m[(size_t)v * HDIM + t];
    int start = ptr[v];
    int cnt = deg[v] - 1;
    for (int i = 0; i < cnt; ++i) {
        int u = csr_src[start + i];
        acc += dv * dis[u] * m[(size_t)u * HDIM + t];
    }
    acc = fmaxf(acc, 0.f);
    xout[(size_t)v * HDIM + t] = acc;
    atomicAdd(&pooled[batch[v] * HDIM + t], acc);
}

// classifier: mean-pool finalize + 2-layer MLP; block per graph
__global__ __launch_bounds__(H2) void k_cls(const float* __restrict__ pooled,
                                            const float* __restrict__ counts,
                                            const float* __restrict__ cw1,
                                            const float* __restrict__ cb1,
                                            const float* __restrict__ cw2,
                                            const float* __restrict__ cb2,
                                            float* __restrict__ out, int B, int C) {
    __shared__ float sp[HDIM];
    __shared__ float sh[H2];
    int g = blockIdx.x, t = threadIdx.x;
    float inv = 1.0f / counts[g];
    sp[t] = pooled[g * HDIM + t] * inv;
    sp[t + H2] = pooled[g * HDIM + t + H2] * inv;
    __syncthreads();
    float acc = cb1[t];
    for (int h = 0; h < HDIM; ++h) acc += sp[h] * cw1[h * H2 + t];
    sh[t] = fmaxf(acc, 0.f);
    __syncthreads();
    if (t < C) {
        float o = cb2[t];
        for (int j = 0; j < H2; ++j) o += sh[j] * cw2[j * C + t];
        out[g * C + t] = o;
    }
    if (g == 0 && t == 0) out[B * C] = 0.f;   // second tuple output (scalar 0)
}

// ---------------------------------------------------------------------------
extern "C" void kernel_launch(void* const* d_in, const int* in_sizes, int n_in,
                              void* d_out, int out_size, void* d_ws, size_t ws_size,
                              hipStream_t stream) {
    const int* x      = (const int*)d_in[0];
    const int* erow   = (const int*)d_in[1];
    const int* batch  = (const int*)d_in[2];
    const float* emb  = (const float*)d_in[3];
    const float* W1   = (const float*)d_in[4];
    const float* b1   = (const float*)d_in[5];
    const float* W2   = (const float*)d_in[6];
    const float* b2   = (const float*)d_in[7];
    const float* W3   = (const float*)d_in[8];
    const float* b3   = (const float*)d_in[9];
    const float* cw1  = (const float*)d_in[10];
    const float* cb1  = (const float*)d_in[11];
    const float* cw2  = (const float*)d_in[12];
    const float* cb2  = (const float*)d_in[13];
    float* out = (float*)d_out;

    const int N = in_sizes[2];
    const int E = in_sizes[1] / 2;
    const int F = in_sizes[0] / N;
    const int V = in_sizes[3] / (F * HDIM);
    const int C = in_sizes[13];
    const int B = (out_size - 1) / C;
    const int* ecol = erow + E;

    // workspace carve (256B aligned)
    char* w = (char*)d_ws;
    auto carve = [&](size_t bytes) {
        void* p = (void*)w;
        w += (bytes + 255) & ~(size_t)255;
        return p;
    };
    float* bufA   = (float*)carve((size_t)N * HDIM * 4);
    float* bufB   = (float*)carve((size_t)N * HDIM * 4);
    float* dis    = (float*)carve((size_t)N * 4);
    float* pooled = (float*)carve((size_t)B * HDIM * 4);
    float* counts = (float*)carve((size_t)B * 4);
    int* deg      = (int*)carve((size_t)N * 4);
    int* ptr      = (int*)carve((size_t)N * 4);
    int* cursor   = (int*)carve((size_t)N * 4);
    int* bsum     = (int*)carve(1024 * 4);
    int* csr      = (int*)carve((size_t)E * 4);

    int nblk = (N + 255) / 256;
    int initspan = (B * HDIM > N) ? B * HDIM : N;

    k_init<<<(initspan + 255) / 256, 256, 0, stream>>>(deg, cursor, pooled, counts,
                                                       N, B * HDIM, B);
    k_deg<<<(E + 255) / 256, 256, 0, stream>>>(ecol, deg, E);
    k_scan1<<<nblk, 256, 0, stream>>>(deg, ptr, bsum, N);
    k_scan2<<<1, 512, 0, stream>>>(bsum, nblk);
    k_scan3<<<nblk, 256, 0, stream>>>(ptr, bsum, N);
    k_fill<<<(E + 255) / 256, 256, 0, stream>>>(erow, ecol, ptr, cursor, csr, E);
    k_dis<<<nblk, 256, 0, stream>>>(deg, dis, batch, counts, N);
    k_atom<<<N, HDIM, 0, stream>>>(x, emb, bufA, N, F, V);

    dim3 ggrid((N + BM - 1) / BM, HDIM / BN);
    // layer 1
    k_gemm<<<ggrid, 256, 0, stream>>>(bufA, W1, bufB, N);
    k_agg<<<N, HDIM, 0, stream>>>(bufB, csr, ptr, deg, dis, b1, batch, bufA, pooled, N);
    // layer 2
    k_gemm<<<ggrid, 256, 0, stream>>>(bufA, W2, bufB, N);
    k_agg<<<N, HDIM, 0, stream>>>(bufB, csr, ptr, deg, dis, b2, batch, bufA, pooled, N);
    // layer 3
    k_gemm<<<ggrid, 256, 0, stream>>>(bufA, W3, bufB, N);
    k_agg<<<N, HDIM, 0, stream>>>(bufB, csr, ptr, deg, dis, b3, batch, bufA, pooled, N);

    k_cls<<<B, H2, 0, stream>>>(pooled, counts, cw1, cb1, cw2, cb2, out, B, C);
}

// Round 2
// 1640.159 us; speedup vs baseline: 1.2248x; 1.2248x over previous
//
#include <hip/hip_runtime.h>
#include <hip/hip_bf16.h>
#include <cstdint>

#define HDIM 256
#define H2   128

using f32x4  = __attribute__((ext_vector_type(4))) float;
using bf16x8 = __attribute__((ext_vector_type(8))) short;   // 8 bf16 in 4 VGPRs

__device__ inline unsigned short f2bf(float f) {            // round-to-nearest-even
    unsigned x = __builtin_bit_cast(unsigned, f);
    return (unsigned short)((x + 0x7fffu + ((x >> 16) & 1u)) >> 16);
}
__device__ inline float bf2f(unsigned short u) {
    unsigned x = ((unsigned)u) << 16;
    return __builtin_bit_cast(float, x);
}

// ---------------------------------------------------------------------------
// init: deg=1 (self loop), cursor=0, pooled=0
__global__ void k_init(int* __restrict__ deg, int* __restrict__ cursor,
                       float* __restrict__ pooled, int n, int bh) {
    int i = blockIdx.x * blockDim.x + threadIdx.x;
    if (i < n) { deg[i] = 1; cursor[i] = 0; }
    if (i < bh) pooled[i] = 0.f;
}

__global__ void k_deg(const int* __restrict__ col, int* __restrict__ deg, int e) {
    int i = blockIdx.x * blockDim.x + threadIdx.x;
    if (i < e) atomicAdd(&deg[col[i]], 1);
}

__global__ void k_scan1(const int* __restrict__ deg, int* __restrict__ ptr,
                        int* __restrict__ bsum, int n) {
    __shared__ int sd[256];
    int i = blockIdx.x * 256 + threadIdx.x;
    int v = (i < n) ? (deg[i] - 1) : 0;
    sd[threadIdx.x] = v;
    __syncthreads();
    for (int off = 1; off < 256; off <<= 1) {
        int t = (threadIdx.x >= off) ? sd[threadIdx.x - off] : 0;
        __syncthreads();
        sd[threadIdx.x] += t;
        __syncthreads();
    }
    if (i < n) ptr[i] = sd[threadIdx.x] - v;
    if (threadIdx.x == 255) bsum[blockIdx.x] = sd[255];
}

__global__ void k_scan2(int* __restrict__ bsum, int nb) {
    __shared__ int sd[512];
    int t = threadIdx.x;
    int v = (t < nb) ? bsum[t] : 0;
    sd[t] = v;
    __syncthreads();
    for (int off = 1; off < 512; off <<= 1) {
        int x = (t >= off) ? sd[t - off] : 0;
        __syncthreads();
        sd[t] += x;
        __syncthreads();
    }
    if (t < nb) bsum[t] = sd[t] - v;
}

__global__ void k_scan3(int* __restrict__ ptr, const int* __restrict__ bsum, int n) {
    int i = blockIdx.x * 256 + threadIdx.x;
    if (i < n) ptr[i] += bsum[blockIdx.x];
}

__global__ void k_fill(const int* __restrict__ row, const int* __restrict__ col,
                       const int* __restrict__ ptr, int* __restrict__ cursor,
                       int* __restrict__ csr_src, int e) {
    int i = blockIdx.x * blockDim.x + threadIdx.x;
    if (i < e) {
        int v = col[i];
        int s = atomicAdd(&cursor[v], 1);
        csr_src[ptr[v] + s] = row[i];
    }
}

__global__ void k_dis(const int* __restrict__ deg, float* __restrict__ dis, int n) {
    int i = blockIdx.x * blockDim.x + threadIdx.x;
    if (i < n) dis[i] = rsqrtf((float)deg[i]);
}

// counts via binary search over sorted batch (atomic-free)
__global__ void k_counts(const int* __restrict__ batch, float* __restrict__ counts,
                         int n, int B) {
    int g = blockIdx.x * blockDim.x + threadIdx.x;
    if (g >= B) return;
    auto lb = [&](int key) {
        int lo = 0, hi = n;
        while (lo < hi) { int mid = (lo + hi) >> 1; if (batch[mid] < key) lo = mid + 1; else hi = mid; }
        return lo;
    };
    counts[g] = (float)(lb(g + 1) - lb(g));
}

// AtomEncoder: wave per node, lane = 4 cols (float4 in, bf16x4 out)
__global__ __launch_bounds__(256) void k_atom(const int* __restrict__ x,
                                              const float* __restrict__ emb,
                                              short* __restrict__ h,
                                              int n, int F, int V) {
    int node = blockIdx.x * 4 + (threadIdx.x >> 6);
    int lane = threadIdx.x & 63;
    if (node >= n) return;
    int xv = x[node * F + (lane < F ? lane : 0)];
    float4 acc = {0.f, 0.f, 0.f, 0.f};
    for (int f = 0; f < F; ++f) {
        int idx = __shfl(xv, f, 64);
        const float4 v = *(const float4*)(emb + ((size_t)f * V + idx) * HDIM + lane * 4);
        acc.x += v.x; acc.y += v.y; acc.z += v.z; acc.w += v.w;
    }
    ushort4 o = { f2bf(acc.x), f2bf(acc.y), f2bf(acc.z), f2bf(acc.w) };
    *(ushort4*)(h + (size_t)node * HDIM + lane * 4) = o;
}

// transpose + convert W (fp32 [K][N]) -> Wt (bf16 [N][K])
__global__ void k_wt(const float* __restrict__ W, short* __restrict__ Wt) {
    int i = blockIdx.x * 256 + threadIdx.x;      // 65536 elements
    int nn = i >> 8, k = i & 255;
    Wt[nn * HDIM + k] = (short)f2bf(W[k * HDIM + nn]);
}

// bf16 MFMA GEMM: C[n,256] = A[n,256] @ W, with Wt = W^T bf16. Block = 4 waves,
// tile 128x128 (2x2 waves of 64x64). Fragments loaded direct from global:
// A frag: row = lane&15, k = (lane>>4)*8 + i (16B contiguous, row-major A)
// B frag: col = lane&15, k = (lane>>4)*8 + i (16B contiguous in Wt)
// D frag: col = lane&15, row = (lane>>4)*4 + reg   [m89-verified]
__global__ __launch_bounds__(256) void k_gemm(const short* __restrict__ A,
                                              const short* __restrict__ Wt,
                                              short* __restrict__ Co, int n) {
    int wid  = threadIdx.x >> 6;
    int lane = threadIdx.x & 63;
    int wr = wid >> 1, wc = wid & 1;
    int row0 = blockIdx.x * 128 + wr * 64;
    int col0 = blockIdx.y * 128 + wc * 64;
    int lm = lane & 15;
    int kg = lane >> 4;
    f32x4 acc[4][4] = {};
    for (int kk = 0; kk < HDIM; kk += 32) {
        bf16x8 a[4], b[4];
#pragma unroll
        for (int i = 0; i < 4; ++i) {
            int r = row0 + i * 16 + lm;
            a[i] = (r < n) ? *(const bf16x8*)(A + (size_t)r * HDIM + kk + kg * 8)
                           : (bf16x8)(short)0;
        }
#pragma unroll
        for (int j = 0; j < 4; ++j) {
            int c = col0 + j * 16 + lm;
            b[j] = *(const bf16x8*)(Wt + (size_t)c * HDIM + kk + kg * 8);
        }
#pragma unroll
        for (int i = 0; i < 4; ++i)
#pragma unroll
            for (int j = 0; j < 4; ++j)
                acc[i][j] = __builtin_amdgcn_mfma_f32_16x16x32_bf16(a[i], b[j], acc[i][j], 0, 0, 0);
    }
#pragma unroll
    for (int i = 0; i < 4; ++i)
#pragma unroll
        for (int j = 0; j < 4; ++j) {
            int c = col0 + j * 16 + lm;
#pragma unroll
            for (int r4 = 0; r4 < 4; ++r4) {
                int r = row0 + i * 16 + kg * 4 + r4;
                if (r < n) Co[(size_t)r * HDIM + c] = (short)f2bf(acc[i][j][r4]);
            }
        }
}

// gather-aggregate (bf16 messages) + bias + relu + fused mean-pool accumulation
// wave per node; lane = 4 cols (ushort4 = 8B loads)
__global__ __launch_bounds__(256) void k_agg(const short* __restrict__ m,
                                             const int* __restrict__ csr_src,
                                             const int* __restrict__ ptr,
                                             const int* __restrict__ deg,
                                             const float* __restrict__ dis,
                                             const float* __restrict__ bias,
                                             const int* __restrict__ batch,
                                             short* __restrict__ xout,
                                             float* __restrict__ pooled, int n) {
    int node = blockIdx.x * 4 + (threadIdx.x >> 6);
    if (node >= n) return;
    int lane = threadIdx.x & 63;
    float dv = dis[node];
    const float4 bv = *(const float4*)(bias + lane * 4);
    ushort4 s = *(const ushort4*)((const unsigned short*)m + (size_t)node * HDIM + lane * 4);
    float sw = dv * dv;
    float a0 = bv.x + sw * bf2f(s.x);
    float a1 = bv.y + sw * bf2f(s.y);
    float a2 = bv.z + sw * bf2f(s.z);
    float a3 = bv.w + sw * bf2f(s.w);
    int start = ptr[node];
    int cnt = deg[node] - 1;
#pragma unroll 4
    for (int i = 0; i < cnt; ++i) {
        int u = csr_src[start + i];
        float w = dv * dis[u];
        ushort4 r = *(const ushort4*)((const unsigned short*)m + (size_t)u * HDIM + lane * 4);
        a0 += w * bf2f(r.x);
        a1 += w * bf2f(r.y);
        a2 += w * bf2f(r.z);
        a3 += w * bf2f(r.w);
    }
    a0 = fmaxf(a0, 0.f); a1 = fmaxf(a1, 0.f); a2 = fmaxf(a2, 0.f); a3 = fmaxf(a3, 0.f);
    ushort4 o = { f2bf(a0), f2bf(a1), f2bf(a2), f2bf(a3) };
    *(ushort4*)((unsigned short*)xout + (size_t)node * HDIM + lane * 4) = o;
    float* pp = pooled + (size_t)batch[node] * HDIM + lane * 4;
    atomicAdd(pp + 0, a0);
    atomicAdd(pp + 1, a1);
    atomicAdd(pp + 2, a2);
    atomicAdd(pp + 3, a3);
}

// classifier: mean-pool finalize + 2-layer MLP; block per graph
__global__ __launch_bounds__(H2) void k_cls(const float* __restrict__ pooled,
                                            const float* __restrict__ counts,
                                            const float* __restrict__ cw1,
                                            const float* __restrict__ cb1,
                                            const float* __restrict__ cw2,
                                            const float* __restrict__ cb2,
                                            float* __restrict__ out, int B, int C) {
    __shared__ float sp[HDIM];
    __shared__ float sh[H2];
    int g = blockIdx.x, t = threadIdx.x;
    float inv = 1.0f / counts[g];
    sp[t] = pooled[g * HDIM + t] * inv;
    sp[t + H2] = pooled[g * HDIM + t + H2] * inv;
    __syncthreads();
    float acc = cb1[t];
    for (int h = 0; h < HDIM; ++h) acc += sp[h] * cw1[h * H2 + t];
    sh[t] = fmaxf(acc, 0.f);
    __syncthreads();
    if (t < C) {
        float o = cb2[t];
        for (int j = 0; j < H2; ++j) o += sh[j] * cw2[j * C + t];
        out[g * C + t] = o;
    }
    if (g == 0 && t == 0) out[B * C] = 0.f;
}

// ---------------------------------------------------------------------------
extern "C" void kernel_launch(void* const* d_in, const int* in_sizes, int n_in,
                              void* d_out, int out_size, void* d_ws, size_t ws_size,
                              hipStream_t stream) {
    const int* x      = (const int*)d_in[0];
    const int* erow   = (const int*)d_in[1];
    const int* batch  = (const int*)d_in[2];
    const float* emb  = (const float*)d_in[3];
    const float* W1   = (const float*)d_in[4];
    const float* b1   = (const float*)d_in[5];
    const float* W2   = (const float*)d_in[6];
    const float* b2   = (const float*)d_in[7];
    const float* W3   = (const float*)d_in[8];
    const float* b3   = (const float*)d_in[9];
    const float* cw1  = (const float*)d_in[10];
    const float* cb1  = (const float*)d_in[11];
    const float* cw2  = (const float*)d_in[12];
    const float* cb2  = (const float*)d_in[13];
    float* out = (float*)d_out;

    const int N = in_sizes[2];
    const int E = in_sizes[1] / 2;
    const int F = in_sizes[0] / N;
    const int V = in_sizes[3] / (F * HDIM);
    const int C = in_sizes[13];
    const int B = (out_size - 1) / C;
    const int* ecol = erow + E;

    char* w = (char*)d_ws;
    auto carve = [&](size_t bytes) {
        void* p = (void*)w;
        w += (bytes + 255) & ~(size_t)255;
        return p;
    };
    short* bufA   = (short*)carve((size_t)N * HDIM * 2);
    short* bufB   = (short*)carve((size_t)N * HDIM * 2);
    short* Wt1    = (short*)carve((size_t)HDIM * HDIM * 2);
    short* Wt2    = (short*)carve((size_t)HDIM * HDIM * 2);
    short* Wt3    = (short*)carve((size_t)HDIM * HDIM * 2);
    float* dis    = (float*)carve((size_t)N * 4);
    float* pooled = (float*)carve((size_t)B * HDIM * 4);
    float* counts = (float*)carve((size_t)B * 4);
    int* deg      = (int*)carve((size_t)N * 4);
    int* ptr      = (int*)carve((size_t)N * 4);
    int* cursor   = (int*)carve((size_t)N * 4);
    int* bsum     = (int*)carve(1024 * 4);
    int* csr      = (int*)carve((size_t)E * 4);

    int nblk = (N + 255) / 256;
    int initspan = (B * HDIM > N) ? B * HDIM : N;

    k_init<<<(initspan + 255) / 256, 256, 0, stream>>>(deg, cursor, pooled, N, B * HDIM);
    k_deg<<<(E + 255) / 256, 256, 0, stream>>>(ecol, deg, E);
    k_scan1<<<nblk, 256, 0, stream>>>(deg, ptr, bsum, N);
    k_scan2<<<1, 512, 0, stream>>>(bsum, nblk);
    k_scan3<<<nblk, 256, 0, stream>>>(ptr, bsum, N);
    k_fill<<<(E + 255) / 256, 256, 0, stream>>>(erow, ecol, ptr, cursor, csr, E);
    k_dis<<<nblk, 256, 0, stream>>>(deg, dis, N);
    k_counts<<<(B + 255) / 256, 256, 0, stream>>>(batch, counts, N, B);
    k_wt<<<HDIM, 256, 0, stream>>>(W1, Wt1);
    k_wt<<<HDIM, 256, 0, stream>>>(W2, Wt2);
    k_wt<<<HDIM, 256, 0, stream>>>(W3, Wt3);
    k_atom<<<(N + 3) / 4, 256, 0, stream>>>(x, emb, bufA, N, F, V);

    dim3 ggrid((N + 127) / 128, 2);
    int agrid = (N + 3) / 4;
    // layer 1
    k_gemm<<<ggrid, 256, 0, stream>>>(bufA, Wt1, bufB, N);
    k_agg<<<agrid, 256, 0, stream>>>(bufB, csr, ptr, deg, dis, b1, batch, bufA, pooled, N);
    // layer 2
    k_gemm<<<ggrid, 256, 0, stream>>>(bufA, Wt2, bufB, N);
    k_agg<<<agrid, 256, 0, stream>>>(bufB, csr, ptr, deg, dis, b2, batch, bufA, pooled, N);
    // layer 3
    k_gemm<<<ggrid, 256, 0, stream>>>(bufA, Wt3, bufB, N);
    k_agg<<<agrid, 256, 0, stream>>>(bufB, csr, ptr, deg, dis, b3, batch, bufA, pooled, N);

    k_cls<<<B, H2, 0, stream>>>(pooled, counts, cw1, cb1, cw2, cb2, out, B, C);
}